// Round 5
// baseline (152.261 us; speedup 1.0000x reference)
//
#include <hip/hip_runtime.h>
#include <hip/hip_bf16.h>
#include <cstddef>

#define B_ 32
#define T_ 128
#define N_ 200
#define FI_ 32
#define FO_ 64
#define K_ 3
#define TT_ 16     // t rows per block
#define NPB_ 25    // n per block (octant)

typedef __attribute__((ext_vector_type(8))) short short8;
typedef __attribute__((ext_vector_type(8))) unsigned short ushort8;
typedef __attribute__((ext_vector_type(4))) float f32x4;

__device__ __forceinline__ unsigned short f2bf(float f) {
    union { __hip_bfloat16 h; unsigned short u; } cv;
    cv.h = __float2bfloat16(f);
    return cv.u;
}

// One-shot: convert w[n,f,i,k] fp32 -> wbf[n][tap][f][i] bf16 (MFMA B-frag
// layout: i contiguous, matching A's k = grp*8+e channel mapping).
__global__ void conv_prep(const float* __restrict__ w,
                          unsigned short* __restrict__ wbf) {
    const int idx = blockIdx.x * 256 + threadIdx.x;  // (n, f)
    if (idx >= N_ * FO_) return;
    const float* wp = w + (size_t)idx * (FI_ * K_);
    float v[FI_ * K_];
    #pragma unroll
    for (int j = 0; j < (FI_ * K_) / 4; ++j) {
        const float4 t4 = *reinterpret_cast<const float4*>(&wp[j * 4]);
        v[j*4+0] = t4.x; v[j*4+1] = t4.y; v[j*4+2] = t4.z; v[j*4+3] = t4.w;
    }
    const int n = idx >> 6, f = idx & 63;
    #pragma unroll
    for (int tap = 0; tap < K_; ++tap) {
        ushort8 u[4];
        #pragma unroll
        for (int i = 0; i < FI_; ++i) u[i >> 3][i & 7] = f2bf(v[i * K_ + tap]);
        unsigned short* dst = wbf + (((size_t)n * K_ + tap) * FO_ + f) * FI_;
        #pragma unroll
        for (int q = 0; q < 4; ++q)
            *reinterpret_cast<ushort8*>(&dst[q * 8]) = u[q];
    }
}

// Block = (b, t-tile of 16, n-octant of 25). 4 waves, each independently
// streams n = nq*25 + {wv, wv+4, ...}: no LDS, no __syncthreads — loads,
// MFMAs and stores from all resident waves interleave freely.
template <bool PREW>
__global__ __launch_bounds__(256, 4) void conv_main(
    const float* __restrict__ x, const float* __restrict__ w,
    const unsigned short* __restrict__ wbf,
    const float* __restrict__ bias, float* __restrict__ out)
{
    const int bid = blockIdx.x;
    const int nq = bid & 7;          // XCD = bid%8 = nq -> W octant L2-resident
    const int tt = (bid >> 3) & 7;
    const int b  = bid >> 6;
    const int t0 = tt * TT_;
    const int lane  = threadIdx.x & 63;
    const int wv    = threadIdx.x >> 6;
    const int row16 = lane & 15;
    const int grp   = lane >> 4;

    #pragma unroll 1
    for (int i = wv; i < NPB_; i += 4) {
        const int n = nq * NPB_ + i;

        // ---- A-frags: x[b, t0+row16+tap-1, n, grp*8..+8] -> bf16 ----
        short8 afr[K_];
        #pragma unroll
        for (int tap = 0; tap < K_; ++tap) {
            const int t = t0 + row16 + tap - 1;
            ushort8 u = (ushort8)0;
            if (t >= 0 && t < T_) {
                const float* xp = &x[(((size_t)b * T_ + t) * N_ + n) * FI_ + grp * 8];
                const float4 v0 = *reinterpret_cast<const float4*>(xp);
                const float4 v1 = *reinterpret_cast<const float4*>(xp + 4);
                u[0] = f2bf(v0.x); u[1] = f2bf(v0.y); u[2] = f2bf(v0.z); u[3] = f2bf(v0.w);
                u[4] = f2bf(v1.x); u[5] = f2bf(v1.y); u[6] = f2bf(v1.z); u[7] = f2bf(v1.w);
            }
            union { ushort8 u8; short8 s8; } cv; cv.u8 = u;
            afr[tap] = cv.s8;
        }

        f32x4 acc[4];
        #pragma unroll
        for (int j = 0; j < 4; ++j) acc[j] = (f32x4){0.f, 0.f, 0.f, 0.f};

        // ---- per j: B-frags (3 taps) + 3 MFMA ----
        #pragma unroll
        for (int j = 0; j < 4; ++j) {
            short8 bfr[K_];
            if constexpr (PREW) {
                #pragma unroll
                for (int tap = 0; tap < K_; ++tap)
                    bfr[tap] = *reinterpret_cast<const short8*>(
                        &wbf[(((size_t)n * K_ + tap) * FO_ + j * 16 + row16) * FI_ + grp * 8]);
            } else {
                const float* wp = &w[((size_t)(n * FO_ + j * 16 + row16)) * (FI_ * K_) + grp * 24];
                float v[24];
                #pragma unroll
                for (int q = 0; q < 6; ++q) {
                    const float4 t4 = *reinterpret_cast<const float4*>(&wp[q * 4]);
                    v[q*4+0] = t4.x; v[q*4+1] = t4.y; v[q*4+2] = t4.z; v[q*4+3] = t4.w;
                }
                #pragma unroll
                for (int tap = 0; tap < K_; ++tap) {
                    ushort8 u;
                    #pragma unroll
                    for (int e = 0; e < 8; ++e) u[e] = f2bf(v[e * K_ + tap]);
                    union { ushort8 u8; short8 s8; } cv; cv.u8 = u;
                    bfr[tap] = cv.s8;
                }
            }
            #pragma unroll
            for (int tap = 0; tap < K_; ++tap)
                acc[j] = __builtin_amdgcn_mfma_f32_16x16x32_bf16(
                    afr[tap], bfr[tap], acc[j], 0, 0, 0);
        }

        // ---- store: C/D col=lane&15 -> f, row=(lane>>4)*4+r -> t (m89) ----
        #pragma unroll
        for (int j = 0; j < 4; ++j) {
            const float bv = bias[n * FO_ + j * 16 + row16];
            #pragma unroll
            for (int r = 0; r < 4; ++r) {
                const int t = t0 + grp * 4 + r;
                out[(((size_t)b * T_ + t) * N_ + n) * FO_ + j * 16 + row16] =
                    acc[j][r] + bv;
            }
        }
    }
}

extern "C" void kernel_launch(void* const* d_in, const int* in_sizes, int n_in,
                              void* d_out, int out_size, void* d_ws, size_t ws_size,
                              hipStream_t stream) {
    const float* x    = (const float*)d_in[0];
    const float* w    = (const float*)d_in[1];
    const float* bias = (const float*)d_in[2];
    float* out = (float*)d_out;

    const size_t W_BF_BYTES = (size_t)N_ * K_ * FO_ * FI_ * 2;  // 2.46 MB
    const int grid = B_ * (T_ / TT_) * 8;  // 2048 blocks: (b, tt, nq), nq fastest

    if (ws_size >= W_BF_BYTES) {
        unsigned short* wbf = (unsigned short*)d_ws;
        conv_prep<<<(N_ * FO_ + 255) / 256, 256, 0, stream>>>(w, wbf);
        conv_main<true><<<grid, 256, 0, stream>>>(x, w, wbf, bias, out);
    } else {
        conv_main<false><<<grid, 256, 0, stream>>>(x, w, nullptr, bias, out);
    }
}

// Round 6
// 144.629 us; speedup vs baseline: 1.0528x; 1.0528x over previous
//
#include <hip/hip_runtime.h>
#include <hip/hip_bf16.h>
#include <cstddef>

#define B_ 32
#define T_ 128
#define N_ 200
#define FI_ 32
#define FO_ 64
#define K_ 3
#define TT_ 16    // t rows per wave

typedef __attribute__((ext_vector_type(8))) short short8;
typedef __attribute__((ext_vector_type(8))) unsigned short ushort8;
typedef __attribute__((ext_vector_type(4))) float f32x4;

__device__ __forceinline__ unsigned short f2bf(float f) {
    union { __hip_bfloat16 h; unsigned short u; } cv;
    cv.h = __float2bfloat16(f);
    return cv.u;
}

// One-shot: w[n,f,i,k] fp32 -> wbf[n][tap][f][i] bf16 (MFMA B-frag layout).
__global__ void conv_prep(const float* __restrict__ w,
                          unsigned short* __restrict__ wbf) {
    const int idx = blockIdx.x * 256 + threadIdx.x;  // (n, f)
    if (idx >= N_ * FO_) return;
    const float* wp = w + (size_t)idx * (FI_ * K_);
    float v[FI_ * K_];
    #pragma unroll
    for (int j = 0; j < (FI_ * K_) / 4; ++j) {
        const float4 t4 = *reinterpret_cast<const float4*>(&wp[j * 4]);
        v[j*4+0] = t4.x; v[j*4+1] = t4.y; v[j*4+2] = t4.z; v[j*4+3] = t4.w;
    }
    const int n = idx >> 6, f = idx & 63;
    #pragma unroll
    for (int tap = 0; tap < K_; ++tap) {
        ushort8 u[4];
        #pragma unroll
        for (int i = 0; i < FI_; ++i) u[i >> 3][i & 7] = f2bf(v[i * K_ + tap]);
        unsigned short* dst = wbf + (((size_t)n * K_ + tap) * FO_ + f) * FI_;
        #pragma unroll
        for (int q = 0; q < 4; ++q)
            *reinterpret_cast<ushort8*>(&dst[q * 8]) = u[q];
    }
}

// One wave = one (b, n, 16-row t-tile) task. Straight-line: 6 x-loads (L3-hot)
// -> cvt -> 12 wbf-loads (L2-hot, 1KB/instr) -> 12 MFMA -> 16 stores.
// No LDS, no barriers; 32 waves/CU (VGPR<=64) hide all latency via TLP.
template <bool PREW>
__global__ __launch_bounds__(256, 8) void conv_main(
    const float* __restrict__ x, const float* __restrict__ w,
    const unsigned short* __restrict__ wbf,
    const float* __restrict__ bias, float* __restrict__ out)
{
    const int bid = blockIdx.x;
    const int ng = bid % 50;             // n-group (4 n per block)
    const int tt = (bid / 50) & 7;       // t-tile
    const int b  = bid / 400;
    const int wv    = threadIdx.x >> 6;
    const int lane  = threadIdx.x & 63;
    const int row16 = lane & 15;
    const int grp   = lane >> 4;
    const int n  = ng * 4 + wv;
    const int t0 = tt * TT_;

    // ---- A-frags: x[b, t0+row16+tap-1, n, grp*8..+8] fp32 -> bf16 ----
    short8 afr[K_];
    #pragma unroll
    for (int tap = 0; tap < K_; ++tap) {
        const int t = t0 + row16 + tap - 1;
        ushort8 u = (ushort8)0;
        if (t >= 0 && t < T_) {
            const float* xp = &x[(((size_t)b * T_ + t) * N_ + n) * FI_ + grp * 8];
            const float4 v0 = *reinterpret_cast<const float4*>(xp);
            const float4 v1 = *reinterpret_cast<const float4*>(xp + 4);
            u[0] = f2bf(v0.x); u[1] = f2bf(v0.y); u[2] = f2bf(v0.z); u[3] = f2bf(v0.w);
            u[4] = f2bf(v1.x); u[5] = f2bf(v1.y); u[6] = f2bf(v1.z); u[7] = f2bf(v1.w);
        }
        union { ushort8 u8; short8 s8; } cv; cv.u8 = u;
        afr[tap] = cv.s8;
    }

    f32x4 acc[4];
    #pragma unroll
    for (int j = 0; j < 4; ++j) acc[j] = (f32x4){0.f, 0.f, 0.f, 0.f};

    // ---- per tap: 4 B-frags (only 4 live at once -> VGPR <= 64) + 4 MFMA ----
    #pragma unroll
    for (int tap = 0; tap < K_; ++tap) {
        #pragma unroll
        for (int j = 0; j < 4; ++j) {
            short8 bfr;
            if constexpr (PREW) {
                bfr = *reinterpret_cast<const short8*>(
                    &wbf[(((size_t)n * K_ + tap) * FO_ + j * 16 + row16) * FI_ + grp * 8]);
            } else {
                const float* wp = &w[((size_t)(n * FO_ + j * 16 + row16)) * (FI_ * K_)
                                     + grp * 8 * K_];
                ushort8 u;
                #pragma unroll
                for (int e = 0; e < 8; ++e) u[e] = f2bf(wp[e * K_ + tap]);
                union { ushort8 u8; short8 s8; } cv; cv.u8 = u;
                bfr = cv.s8;
            }
            acc[j] = __builtin_amdgcn_mfma_f32_16x16x32_bf16(afr[tap], bfr, acc[j], 0, 0, 0);
        }
    }

    // ---- store: C/D col=lane&15 -> f, row=(lane>>4)*4+r -> t (m89) ----
    #pragma unroll
    for (int j = 0; j < 4; ++j) {
        const float bv = bias[n * FO_ + j * 16 + row16];
        #pragma unroll
        for (int r = 0; r < 4; ++r) {
            const int t = t0 + grp * 4 + r;
            out[(((size_t)b * T_ + t) * N_ + n) * FO_ + j * 16 + row16] =
                acc[j][r] + bv;
        }
    }
}

extern "C" void kernel_launch(void* const* d_in, const int* in_sizes, int n_in,
                              void* d_out, int out_size, void* d_ws, size_t ws_size,
                              hipStream_t stream) {
    const float* x    = (const float*)d_in[0];
    const float* w    = (const float*)d_in[1];
    const float* bias = (const float*)d_in[2];
    float* out = (float*)d_out;

    const size_t W_BF_BYTES = (size_t)N_ * K_ * FO_ * FI_ * 2;  // 2.46 MB
    const int grid = B_ * (T_ / TT_) * 50;  // 12800 blocks: (b, tt, ng), ng fastest

    if (ws_size >= W_BF_BYTES) {
        unsigned short* wbf = (unsigned short*)d_ws;
        conv_prep<<<(N_ * FO_ + 255) / 256, 256, 0, stream>>>(w, wbf);
        conv_main<true><<<grid, 256, 0, stream>>>(x, w, wbf, bias, out);
    } else {
        conv_main<false><<<grid, 256, 0, stream>>>(x, w, nullptr, bias, out);
    }
}

// Round 7
// 115.225 us; speedup vs baseline: 1.3214x; 1.2552x over previous
//
#include <hip/hip_runtime.h>
#include <hip/hip_bf16.h>
#include <cstddef>

#define B_ 32
#define T_ 128
#define N_ 200
#define FI_ 32
#define FO_ 64
#define K_ 3
#define TILE_T_ 64               // t rows per block (4 waves x 16)
#define AROW_ 40                 // LDS row stride (ushorts): 80B -> 2-way max
#define A_ROWS_ (TILE_T_ + 2)    // t = t0-1 .. t0+64

typedef __attribute__((ext_vector_type(8))) short short8;
typedef __attribute__((ext_vector_type(8))) unsigned short ushort8;
typedef __attribute__((ext_vector_type(4))) float f32x4;

__device__ __forceinline__ unsigned short f2bf(float f) {
    union { __hip_bfloat16 h; unsigned short u; } cv;
    cv.h = __float2bfloat16(f);
    return cv.u;
}

// One-shot: w[n,f,i,k] fp32 -> wbf[n][tap][f][i] bf16 (MFMA B-frag layout).
__global__ void conv_prep(const float* __restrict__ w,
                          unsigned short* __restrict__ wbf) {
    const int idx = blockIdx.x * 256 + threadIdx.x;  // (n, f)
    if (idx >= N_ * FO_) return;
    const float* wp = w + (size_t)idx * (FI_ * K_);
    float v[FI_ * K_];
    #pragma unroll
    for (int j = 0; j < (FI_ * K_) / 4; ++j) {
        const float4 t4 = *reinterpret_cast<const float4*>(&wp[j * 4]);
        v[j*4+0] = t4.x; v[j*4+1] = t4.y; v[j*4+2] = t4.z; v[j*4+3] = t4.w;
    }
    const int n = idx >> 6, f = idx & 63;
    #pragma unroll
    for (int tap = 0; tap < K_; ++tap) {
        ushort8 u[4];
        #pragma unroll
        for (int i = 0; i < FI_; ++i) u[i >> 3][i & 7] = f2bf(v[i * K_ + tap]);
        unsigned short* dst = wbf + (((size_t)n * K_ + tap) * FO_ + f) * FI_;
        #pragma unroll
        for (int q = 0; q < 4; ++q)
            *reinterpret_cast<ushort8*>(&dst[q * 8]) = u[q];
    }
}

// Block = (b, t-half, n): 4 waves x (16 t-rows x 64 f). x staged in LDS once
// (shared across taps/waves); W b-frags global->reg (L2-hot, 1KB coalesced),
// taps 0-1 issued BEFORE the barrier so their latency hides under staging.
template <bool PREW>
__global__ __launch_bounds__(256, 6) void conv_main(
    const float* __restrict__ x, const float* __restrict__ w,
    const unsigned short* __restrict__ wbf,
    const float* __restrict__ bias, float* __restrict__ out)
{
    __shared__ __align__(16) unsigned short lds[A_ROWS_ * AROW_];  // 5280 B

    const int bid = blockIdx.x;
    const int n = bid % N_;
    const int rest = bid / N_;
    const int tile = rest & 1;
    const int b = rest >> 1;
    const int t0 = tile * TILE_T_;
    const int tid = threadIdx.x;
    const int lane = tid & 63;
    const int wv = tid >> 6;
    const int row16 = lane & 15;
    const int grp = lane >> 4;

    // ---- W b-frags for taps 0,1 -> registers (independent of barrier) ----
    short8 bfr0[4], bfr1[4];
    if constexpr (PREW) {
        #pragma unroll
        for (int j = 0; j < 4; ++j) {
            const size_t base = ((size_t)n * K_ * FO_ + (size_t)(j * 16 + row16)) * FI_ + grp * 8;
            bfr0[j] = *reinterpret_cast<const short8*>(&wbf[base]);
            bfr1[j] = *reinterpret_cast<const short8*>(&wbf[base + (size_t)FO_ * FI_]);
        }
    }

    // ---- stage x rows t0-1 .. t0+64 as bf16 into LDS ----
    for (int s = tid; s < A_ROWS_ * 4; s += 256) {
        const int rr = s >> 2, q = s & 3;
        const int t = t0 + rr - 1;
        ushort8 u = (ushort8)0;
        if (t >= 0 && t < T_) {
            const float* xp = &x[(((size_t)b * T_ + t) * N_ + n) * FI_ + q * 8];
            const float4 v0 = *reinterpret_cast<const float4*>(xp);
            const float4 v1 = *reinterpret_cast<const float4*>(xp + 4);
            u[0] = f2bf(v0.x); u[1] = f2bf(v0.y); u[2] = f2bf(v0.z); u[3] = f2bf(v0.w);
            u[4] = f2bf(v1.x); u[5] = f2bf(v1.y); u[6] = f2bf(v1.z); u[7] = f2bf(v1.w);
        }
        *reinterpret_cast<ushort8*>(&lds[rr * AROW_ + q * 8]) = u;
    }

    __syncthreads();

    f32x4 acc[4];
    #pragma unroll
    for (int j = 0; j < 4; ++j) acc[j] = (f32x4){0.f, 0.f, 0.f, 0.f};

    // tap 2 b-frags: load now, consumed after taps 0-1 (latency hidden by MFMA)
    short8 bfr2[4];
    if constexpr (PREW) {
        #pragma unroll
        for (int j = 0; j < 4; ++j)
            bfr2[j] = *reinterpret_cast<const short8*>(
                &wbf[((size_t)n * K_ * FO_ + 2 * FO_ + (size_t)(j * 16 + row16)) * FI_ + grp * 8]);
    } else {
        // fallback: inline-convert all taps from fp32 w
        #pragma unroll
        for (int j = 0; j < 4; ++j) {
            const float* wp = &w[((size_t)(n * FO_ + j * 16 + row16)) * (FI_ * K_) + grp * 8 * K_];
            ushort8 u0, u1, u2;
            #pragma unroll
            for (int e = 0; e < 8; ++e) {
                u0[e] = f2bf(wp[e * K_ + 0]);
                u1[e] = f2bf(wp[e * K_ + 1]);
                u2[e] = f2bf(wp[e * K_ + 2]);
            }
            union { ushort8 u8; short8 s8; } c0, c1, c2;
            c0.u8 = u0; c1.u8 = u1; c2.u8 = u2;
            bfr0[j] = c0.s8; bfr1[j] = c1.s8; bfr2[j] = c2.s8;
        }
    }

    // ---- MFMA: wave wv owns t rows [t0+wv*16, +16); A row = lane row16 ----
    {
        const short8 a0 = *reinterpret_cast<const short8*>(
            &lds[(wv * 16 + row16 + 0) * AROW_ + grp * 8]);
        #pragma unroll
        for (int j = 0; j < 4; ++j)
            acc[j] = __builtin_amdgcn_mfma_f32_16x16x32_bf16(a0, bfr0[j], acc[j], 0, 0, 0);
        const short8 a1 = *reinterpret_cast<const short8*>(
            &lds[(wv * 16 + row16 + 1) * AROW_ + grp * 8]);
        #pragma unroll
        for (int j = 0; j < 4; ++j)
            acc[j] = __builtin_amdgcn_mfma_f32_16x16x32_bf16(a1, bfr1[j], acc[j], 0, 0, 0);
        const short8 a2 = *reinterpret_cast<const short8*>(
            &lds[(wv * 16 + row16 + 2) * AROW_ + grp * 8]);
        #pragma unroll
        for (int j = 0; j < 4; ++j)
            acc[j] = __builtin_amdgcn_mfma_f32_16x16x32_bf16(a2, bfr2[j], acc[j], 0, 0, 0);
    }

    // ---- store: C/D col=lane&15 -> f, row=grp*4+r -> t offset (m89) ----
    #pragma unroll
    for (int j = 0; j < 4; ++j) {
        const float bv = bias[n * FO_ + j * 16 + row16];
        #pragma unroll
        for (int r = 0; r < 4; ++r) {
            const int t = t0 + wv * 16 + grp * 4 + r;
            out[(((size_t)b * T_ + t) * N_ + n) * FO_ + j * 16 + row16] =
                acc[j][r] + bv;
        }
    }
}

extern "C" void kernel_launch(void* const* d_in, const int* in_sizes, int n_in,
                              void* d_out, int out_size, void* d_ws, size_t ws_size,
                              hipStream_t stream) {
    const float* x    = (const float*)d_in[0];
    const float* w    = (const float*)d_in[1];
    const float* bias = (const float*)d_in[2];
    float* out = (float*)d_out;

    const size_t W_BF_BYTES = (size_t)N_ * K_ * FO_ * FI_ * 2;  // 2.46 MB
    const int grid = B_ * 2 * N_;  // 12800 blocks: (b, tile, n), n fastest

    if (ws_size >= W_BF_BYTES) {
        unsigned short* wbf = (unsigned short*)d_ws;
        conv_prep<<<(N_ * FO_ + 255) / 256, 256, 0, stream>>>(w, wbf);
        conv_main<true><<<grid, 256, 0, stream>>>(x, w, wbf, bias, out);
    } else {
        conv_main<false><<<grid, 256, 0, stream>>>(x, w, nullptr, bias, out);
    }
}

// Round 8
// 94.702 us; speedup vs baseline: 1.6078x; 1.2167x over previous
//
#include <hip/hip_runtime.h>
#include <hip/hip_bf16.h>
#include <cstddef>

#define B_ 32
#define T_ 128
#define N_ 200
#define FI_ 32
#define FO_ 64
#define K_ 3

typedef __attribute__((ext_vector_type(8))) short short8;
typedef __attribute__((ext_vector_type(8))) unsigned short ushort8;
typedef __attribute__((ext_vector_type(4))) float f32x4;

// LDS layout (ushort units). Row stride 40 ushorts = 80 B: bank advance
// 20 mod 32 per row -> max 2-way aliasing (free, m136).
#define AROW_ 40
#define A_ROWS_ (T_ + 2)            // t = -1 .. 128, zero-padded edges
#define B_OFF_ (A_ROWS_ * AROW_)    // 5200
#define BROW_ 40
#define BK_SZ_ (FO_ * BROW_)        // 2560 ushorts per tap k

__device__ __forceinline__ unsigned short f2bf(float f) {
    union { __hip_bfloat16 h; unsigned short u; } cv;
    cv.h = __float2bfloat16(f);
    return cv.u;
}

// One-shot: w[n,f,i,k] fp32 -> wbf[n][tap][f][i] bf16 (MFMA B-frag layout).
__global__ void conv_prep(const float* __restrict__ w,
                          unsigned short* __restrict__ wbf) {
    const int idx = blockIdx.x * 256 + threadIdx.x;  // (n, f)
    if (idx >= N_ * FO_) return;
    const float* wp = w + (size_t)idx * (FI_ * K_);
    float v[FI_ * K_];
    #pragma unroll
    for (int j = 0; j < (FI_ * K_) / 4; ++j) {
        const float4 t4 = *reinterpret_cast<const float4*>(&wp[j * 4]);
        v[j*4+0] = t4.x; v[j*4+1] = t4.y; v[j*4+2] = t4.z; v[j*4+3] = t4.w;
    }
    const int n = idx >> 6, f = idx & 63;
    #pragma unroll
    for (int tap = 0; tap < K_; ++tap) {
        ushort8 u[4];
        #pragma unroll
        for (int i = 0; i < FI_; ++i) u[i >> 3][i & 7] = f2bf(v[i * K_ + tap]);
        unsigned short* dst = wbf + (((size_t)n * K_ + tap) * FO_ + f) * FI_;
        #pragma unroll
        for (int q = 0; q < 4; ++q)
            *reinterpret_cast<ushort8*>(&dst[q * 8]) = u[q];
    }
}

// R3 skeleton: one block per (b, n), full T=128 x all 64 f via MFMA.
// 4 waves x 32 t-rows; 3 taps x 2 m-frags x 4 n-frags = 24 mfma/wave.
// Changes vs R3: (1) W staged from pre-converted wbf (pure memcpy, no cvt);
// (2) 6 blocks/CU (LDS 25.76KB allows exactly 6; nothing held across barrier).
template <bool PREW>
__global__ __launch_bounds__(256, 6) void conv_main(
    const float* __restrict__ x, const float* __restrict__ w,
    const unsigned short* __restrict__ wbf,
    const float* __restrict__ bias, float* __restrict__ out)
{
    __shared__ __align__(16) unsigned short lds[B_OFF_ + K_ * BK_SZ_];  // 25760 B

    const int bid = blockIdx.x;
    const int b = bid & 31;    // batch (b-fastest: 32 consecutive blocks share n)
    const int n = bid >> 5;
    const int tid = threadIdx.x;
    const int lane = tid & 63;
    const int wv = tid >> 6;

    // ---- stage W -> B region of LDS ----
    if constexpr (PREW) {
        // dense [tap][f][i] -> padded rows (BROW_=40): 768 ushort8 slots
        const unsigned short* src = wbf + (size_t)n * K_ * FO_ * FI_;
        #pragma unroll
        for (int ss = 0; ss < 3; ++ss) {
            const int s = tid + ss * 256;
            const int tf = s >> 2;        // (tap, f) row 0..191
            const int q = s & 3;
            const ushort8 u = *reinterpret_cast<const ushort8*>(&src[tf * FI_ + q * 8]);
            *reinterpret_cast<ushort8*>(
                &lds[B_OFF_ + (tf >> 6) * BK_SZ_ + (tf & 63) * BROW_ + q * 8]) = u;
        }
    } else {
        // R3 fallback: inline fp32->bf16 conversion
        const int f = tid >> 2;
        const int i0 = (tid & 3) * 8;
        const float* wp = w + ((size_t)n * FO_ + f) * (FI_ * K_) + (size_t)i0 * K_;
        float v[24];
        #pragma unroll
        for (int j = 0; j < 6; ++j) {
            const float4 t4 = *reinterpret_cast<const float4*>(&wp[j * 4]);
            v[j*4+0] = t4.x; v[j*4+1] = t4.y; v[j*4+2] = t4.z; v[j*4+3] = t4.w;
        }
        #pragma unroll
        for (int k = 0; k < K_; ++k) {
            ushort8 u;
            #pragma unroll
            for (int j = 0; j < 8; ++j) u[j] = f2bf(v[j * K_ + k]);
            *reinterpret_cast<ushort8*>(&lds[B_OFF_ + k * BK_SZ_ + f * BROW_ + i0]) = u;
        }
    }

    // ---- stage x[b, t, n, 0:32] for t = -1..128 as bf16 (rows of 32ch) ----
    const float* xb = x + ((size_t)b * T_ * N_ + n) * FI_;
    for (int s = tid; s < A_ROWS_ * 4; s += 256) {
        const int rr = s >> 2, q = s & 3;
        const int t = rr - 1;
        ushort8 u = (ushort8)0;
        if (t >= 0 && t < T_) {
            const float4 v0 = *reinterpret_cast<const float4*>(
                &xb[(size_t)t * N_ * FI_ + q * 8]);
            const float4 v1 = *reinterpret_cast<const float4*>(
                &xb[(size_t)t * N_ * FI_ + q * 8 + 4]);
            u[0] = f2bf(v0.x); u[1] = f2bf(v0.y); u[2] = f2bf(v0.z); u[3] = f2bf(v0.w);
            u[4] = f2bf(v1.x); u[5] = f2bf(v1.y); u[6] = f2bf(v1.z); u[7] = f2bf(v1.w);
        }
        *reinterpret_cast<ushort8*>(&lds[rr * AROW_ + q * 8]) = u;
    }

    __syncthreads();

    f32x4 acc[2][4];
    #pragma unroll
    for (int m = 0; m < 2; ++m)
        #pragma unroll
        for (int j = 0; j < 4; ++j)
            acc[m][j] = (f32x4){0.f, 0.f, 0.f, 0.f};

    const int row16 = lane & 15;
    const int grp = lane >> 4;

    // out[t] += x[t + k - 1] @ W_k ; LDS A-row = t + k (t offset by +1 for pad)
    #pragma unroll
    for (int k = 0; k < K_; ++k) {
        const short8 a0 = *reinterpret_cast<const short8*>(
            &lds[(wv * 32 + 0  + row16 + k) * AROW_ + grp * 8]);
        const short8 a1 = *reinterpret_cast<const short8*>(
            &lds[(wv * 32 + 16 + row16 + k) * AROW_ + grp * 8]);
        #pragma unroll
        for (int j = 0; j < 4; ++j) {
            const short8 bf = *reinterpret_cast<const short8*>(
                &lds[B_OFF_ + k * BK_SZ_ + (j * 16 + row16) * BROW_ + grp * 8]);
            acc[0][j] = __builtin_amdgcn_mfma_f32_16x16x32_bf16(a0, bf, acc[0][j], 0, 0, 0);
            acc[1][j] = __builtin_amdgcn_mfma_f32_16x16x32_bf16(a1, bf, acc[1][j], 0, 0, 0);
        }
    }

    // ---- epilogue: C/D layout col=lane&15, row=(lane>>4)*4+reg (m89) ----
    #pragma unroll
    for (int j = 0; j < 4; ++j) {
        const float bv = bias[n * FO_ + j * 16 + row16];
        #pragma unroll
        for (int m = 0; m < 2; ++m) {
            #pragma unroll
            for (int r = 0; r < 4; ++r) {
                const int t = wv * 32 + m * 16 + grp * 4 + r;
                out[(((size_t)b * T_ + t) * N_ + n) * FO_ + j * 16 + row16] =
                    acc[m][j][r] + bv;
            }
        }
    }
}

extern "C" void kernel_launch(void* const* d_in, const int* in_sizes, int n_in,
                              void* d_out, int out_size, void* d_ws, size_t ws_size,
                              hipStream_t stream) {
    const float* x    = (const float*)d_in[0];
    const float* w    = (const float*)d_in[1];
    const float* bias = (const float*)d_in[2];
    float* out = (float*)d_out;

    const size_t W_BF_BYTES = (size_t)N_ * K_ * FO_ * FI_ * 2;  // 2.46 MB
    const int grid = B_ * N_;  // 6400 blocks: (n, b), b fastest (R3 order)

    if (ws_size >= W_BF_BYTES) {
        unsigned short* wbf = (unsigned short*)d_ws;
        conv_prep<<<(N_ * FO_ + 255) / 256, 256, 0, stream>>>(w, wbf);
        conv_main<true><<<grid, 256, 0, stream>>>(x, w, wbf, bias, out);
    } else {
        conv_main<false><<<grid, 256, 0, stream>>>(x, w, nullptr, bias, out);
    }
}